// Round 5
// baseline (68.878 us; speedup 1.0000x reference)
//
#include <hip/hip_runtime.h>

#define BS  16
#define NN  256
#define HID 128

// ---------------------------------------------------------------------------
// K1: 8 rows per block, 512 threads. Computes h (LDS only), ai (global),
// ajT[b][k][j] (global, transposed), and g = h@W_out (global fold so the
// attention kernel can emit `out` directly).
// ---------------------------------------------------------------------------
__global__ __launch_bounds__(512) void gat_k1(
    const float* __restrict__ x, const float* __restrict__ W_fc,
    const float* __restrict__ b_fc, const float* __restrict__ W_a1,
    const float* __restrict__ b_a1, const float* __restrict__ W_out,
    float* __restrict__ ai, float* __restrict__ ajT, float* __restrict__ g)
{
    __shared__ __align__(16) float xs[8][HID];
    __shared__ __align__(16) float hs[8][HID];
    const int tid = threadIdx.x;
    const int k   = tid & 127;
    const int q   = tid >> 7;          // 0..3
    const int r0  = blockIdx.x * 8;    // flat row = b*NN + n0
    const int b   = r0 >> 8;
    const int n0  = r0 & 255;

    for (int t = tid; t < 8 * HID; t += 512)
        xs[t >> 7][t & 127] = x[r0 * HID + t];
    __syncthreads();

    // ---- phase 1: h rows 2q, 2q+1 (stays in LDS) ----
    {
        const float bf = b_fc[k];
        float a0 = bf, a1 = bf;
        #pragma unroll 4
        for (int d0 = 0; d0 < HID; d0 += 4) {
            const float w0 = W_fc[(d0 + 0) * HID + k];
            const float w1 = W_fc[(d0 + 1) * HID + k];
            const float w2 = W_fc[(d0 + 2) * HID + k];
            const float w3 = W_fc[(d0 + 3) * HID + k];
            const float4 x0 = *(const float4*)&xs[2 * q + 0][d0];
            const float4 x1 = *(const float4*)&xs[2 * q + 1][d0];
            a0 += x0.x * w0 + x0.y * w1 + x0.z * w2 + x0.w * w3;
            a1 += x1.x * w0 + x1.y * w1 + x1.z * w2 + x1.w * w3;
        }
        hs[2 * q + 0][k] = a0;
        hs[2 * q + 1][k] = a1;
    }
    __syncthreads();

    // ---- phase 2a: q0/q1 -> ai (global); q2/q3 -> ajT (global, transposed) ----
    {
        const int is_aj  = q >> 1;
        const int rbase  = (q & 1) * 4;
        const float* Wp  = W_a1 + is_aj * HID * HID;
        const float bias = is_aj ? 0.f : b_a1[k];
        float acc[4] = {bias, bias, bias, bias};
        #pragma unroll 4
        for (int d0 = 0; d0 < HID; d0 += 4) {
            const float w0 = Wp[(d0 + 0) * HID + k];
            const float w1 = Wp[(d0 + 1) * HID + k];
            const float w2 = Wp[(d0 + 2) * HID + k];
            const float w3 = Wp[(d0 + 3) * HID + k];
            #pragma unroll
            for (int r = 0; r < 4; ++r) {
                const float4 hv = *(const float4*)&hs[rbase + r][d0];
                acc[r] += hv.x * w0 + hv.y * w1 + hv.z * w2 + hv.w * w3;
            }
        }
        if (!is_aj) {
            #pragma unroll
            for (int r = 0; r < 4; ++r)
                ai[(r0 + rbase + r) * HID + k] = acc[r];
        } else {
            const float4 v = {acc[0], acc[1], acc[2], acc[3]};
            *(float4*)&ajT[(b * HID + k) * NN + n0 + rbase] = v;
        }
    }

    // ---- phase 2b: g rows 2q,2q+1 = hs @ W_out ----
    {
        float a0 = 0.f, a1 = 0.f;
        #pragma unroll 4
        for (int d0 = 0; d0 < HID; d0 += 4) {
            const float w0 = W_out[(d0 + 0) * HID + k];
            const float w1 = W_out[(d0 + 1) * HID + k];
            const float w2 = W_out[(d0 + 2) * HID + k];
            const float w3 = W_out[(d0 + 3) * HID + k];
            const float4 h0 = *(const float4*)&hs[2 * q + 0][d0];
            const float4 h1 = *(const float4*)&hs[2 * q + 1][d0];
            a0 += h0.x * w0 + h0.y * w1 + h0.z * w2 + h0.w * w3;
            a1 += h1.x * w0 + h1.y * w1 + h1.z * w2 + h1.w * w3;
        }
        g[(r0 + 2 * q + 0) * HID + k] = a0;
        g[(r0 + 2 * q + 1) * HID + k] = a1;
    }
}

// ---------------------------------------------------------------------------
// K2: per (batch, 8-row i-tile), 256 threads (4 waves). Phase A: 2 i-rows
// per wave (one aj ds_read feeds both rows -> LDS pipe no longer the
// bottleneck), ai/w2 via wave-uniform scalar loads, aj LDS-chunked with reg
// prefetch. Wave-local softmax. Phase B: j-split (g read exactly once per
// block) + LDS reduction. out = attn@g + b_out.
// ---------------------------------------------------------------------------
__global__ __launch_bounds__(256, 4) void gat_k2(
    const float* __restrict__ ai, const float* __restrict__ ajT,
    const float* __restrict__ g,  const int* __restrict__ adj,
    const float* __restrict__ w_a2, const float* __restrict__ b_a2,
    const float* __restrict__ b_out, float* __restrict__ out)
{
    __shared__ __align__(16) float ov[32 * NN];   // 32KB: ajs; later p_lds+red

    const int tid  = threadIdx.x;
    const int b    = blockIdx.x >> 5;
    const int i0   = (blockIdx.x & 31) * 8;
    const int wid  = tid >> 6, lane = tid & 63;
    const int j0   = lane * 4;

    // staging map (bank-conflict-free): thread covers rows srow, cols
    // (tid&7)*4 + 32u, u=0..7 within each 32x256 chunk.
    const int srow = tid >> 3;
    const int sc0  = (tid & 7) * 4;
    const float* ajbase = ajT + (b * HID + srow) * NN + sc0;

    float4 st[8];
    #pragma unroll
    for (int u = 0; u < 8; ++u) st[u] = *(const float4*)(ajbase + 32 * u);

    // wave-uniform scalar bases for ai rows 2wid, 2wid+1
    const int rb = __builtin_amdgcn_readfirstlane((b * NN + i0 + 2 * wid) * HID);
    const float* ai0 = ai + rb;
    const float* ai1 = ai + rb + HID;

    float4 acc0 = {0.f, 0.f, 0.f, 0.f}, acc1 = {0.f, 0.f, 0.f, 0.f};
    for (int kc = 0; kc < 4; ++kc) {
        __syncthreads();   // previous chunk fully consumed
        #pragma unroll
        for (int u = 0; u < 8; ++u)
            *(float4*)&ov[srow * NN + sc0 + 32 * u] = st[u];
        if (kc < 3) {
            const float* nxt = ajbase + (kc + 1) * 32 * NN;
            #pragma unroll
            for (int u = 0; u < 8; ++u) st[u] = *(const float4*)(nxt + 32 * u);
        }
        __syncthreads();   // chunk ready
        const int kb = kc * 32;
        #pragma unroll 8
        for (int kk = 0; kk < 32; ++kk) {
            const float4 a4 = *(const float4*)&ov[kk * NN + j0];
            const float v0 = ai0[kb + kk];
            const float v1 = ai1[kb + kk];
            const float wv = w_a2[kb + kk];
            acc0.x += fmaxf(v0 + a4.x, 0.f) * wv;
            acc0.y += fmaxf(v0 + a4.y, 0.f) * wv;
            acc0.z += fmaxf(v0 + a4.z, 0.f) * wv;
            acc0.w += fmaxf(v0 + a4.w, 0.f) * wv;
            acc1.x += fmaxf(v1 + a4.x, 0.f) * wv;
            acc1.y += fmaxf(v1 + a4.y, 0.f) * wv;
            acc1.z += fmaxf(v1 + a4.z, 0.f) * wv;
            acc1.w += fmaxf(v1 + a4.w, 0.f) * wv;
        }
    }
    __syncthreads();       // all ajs reads done; ov reusable

    float* p_lds = ov;            // [8][NN]   (8KB)
    float* red   = ov + 8 * NN;   // [2][8][128] (8KB)

    // ---- mask + wave-local softmax for rows 2wid, 2wid+1 ----
    {
        const float ba2 = b_a2[0];
        const int arow = (b * NN + i0 + 2 * wid) * NN + j0;
        const int4 m0 = *(const int4*)(adj + arow);
        const int4 m1 = *(const int4*)(adj + arow + NN);
        const float e0 = m0.x ? acc0.x + ba2 : -1e9f;
        const float e1 = m0.y ? acc0.y + ba2 : -1e9f;
        const float e2 = m0.z ? acc0.z + ba2 : -1e9f;
        const float e3 = m0.w ? acc0.w + ba2 : -1e9f;
        const float f0 = m1.x ? acc1.x + ba2 : -1e9f;
        const float f1 = m1.y ? acc1.y + ba2 : -1e9f;
        const float f2 = m1.z ? acc1.z + ba2 : -1e9f;
        const float f3 = m1.w ? acc1.w + ba2 : -1e9f;
        float mx0 = fmaxf(fmaxf(e0, e1), fmaxf(e2, e3));
        float mx1 = fmaxf(fmaxf(f0, f1), fmaxf(f2, f3));
        #pragma unroll
        for (int off = 32; off; off >>= 1) {
            mx0 = fmaxf(mx0, __shfl_xor(mx0, off));
            mx1 = fmaxf(mx1, __shfl_xor(mx1, off));
        }
        const float p0 = __expf(e0 - mx0), p1 = __expf(e1 - mx0);
        const float p2 = __expf(e2 - mx0), p3 = __expf(e3 - mx0);
        const float q0 = __expf(f0 - mx1), q1 = __expf(f1 - mx1);
        const float q2 = __expf(f2 - mx1), q3 = __expf(f3 - mx1);
        float s0 = (p0 + p1) + (p2 + p3);
        float s1 = (q0 + q1) + (q2 + q3);
        #pragma unroll
        for (int off = 32; off; off >>= 1) {
            s0 += __shfl_xor(s0, off);
            s1 += __shfl_xor(s1, off);
        }
        const float i0v = 1.f / s0, i1v = 1.f / s1;
        const float4 pv0 = {p0 * i0v, p1 * i0v, p2 * i0v, p3 * i0v};
        const float4 pv1 = {q0 * i1v, q1 * i1v, q2 * i1v, q3 * i1v};
        *(float4*)&p_lds[(2 * wid + 0) * NN + j0] = pv0;
        *(float4*)&p_lds[(2 * wid + 1) * NN + j0] = pv1;
    }
    __syncthreads();

    // ---- phase B: out rows i0..i0+7 = attn @ g, j split across q-halves ----
    const int k = tid & 127, qh = tid >> 7;   // qh in {0,1}: j in [128qh,128qh+128)
    {
        float acc[8] = {0.f, 0.f, 0.f, 0.f, 0.f, 0.f, 0.f, 0.f};
        const float* gb = g + (b * NN + qh * 128) * HID + k;
        const float* pq = p_lds + qh * 128;
        #pragma unroll 4
        for (int jq = 0; jq < 32; ++jq) {
            const float g0 = gb[(4 * jq + 0) * HID];
            const float g1 = gb[(4 * jq + 1) * HID];
            const float g2 = gb[(4 * jq + 2) * HID];
            const float g3 = gb[(4 * jq + 3) * HID];
            #pragma unroll
            for (int r = 0; r < 8; ++r) {
                const float4 pv = *(const float4*)&pq[r * NN + 4 * jq];
                acc[r] += pv.x * g0 + pv.y * g1 + pv.z * g2 + pv.w * g3;
            }
        }
        #pragma unroll
        for (int r = 0; r < 8; ++r) red[(qh * 8 + r) * 128 + k] = acc[r];
    }
    __syncthreads();
    if (qh == 0) {
        const float bo = b_out[k];
        #pragma unroll
        for (int r = 0; r < 8; ++r)
            out[(b * NN + i0 + r) * HID + k] =
                red[r * 128 + k] + red[(8 + r) * 128 + k] + bo;
    }
}

extern "C" void kernel_launch(void* const* d_in, const int* in_sizes, int n_in,
                              void* d_out, int out_size, void* d_ws, size_t ws_size,
                              hipStream_t stream) {
    const float* x     = (const float*)d_in[0];
    const int*   adj   = (const int*)  d_in[1];
    const float* W_fc  = (const float*)d_in[2];
    const float* b_fc  = (const float*)d_in[3];
    const float* W_a1  = (const float*)d_in[4];
    const float* b_a1  = (const float*)d_in[5];
    const float* w_a2  = (const float*)d_in[6];
    const float* b_a2  = (const float*)d_in[7];
    const float* W_out = (const float*)d_in[8];
    const float* b_out = (const float*)d_in[9];
    float* out = (float*)d_out;

    float* ws  = (float*)d_ws;
    float* ai  = ws;                      // 16*256*128
    float* ajT = ws + BS * NN * HID;      // +524288, ajT[b][k][j]
    float* g   = ws + 2 * BS * NN * HID;  // +1048576, g = h@W_out

    gat_k1<<<BS * NN / 8, 512, 0, stream>>>(x, W_fc, b_fc, W_a1, b_a1, W_out,
                                            ai, ajT, g);
    gat_k2<<<BS * (NN / 8), 256, 0, stream>>>(ai, ajT, g, adj, w_a2, b_a2,
                                              b_out, out);
}

// Round 6
// 66.209 us; speedup vs baseline: 1.0403x; 1.0403x over previous
//
#include <hip/hip_runtime.h>

#define BS  16
#define NN  256
#define HID 128

// XCD-aware swizzle: 512 blocks, 8 XCDs -> XCD x gets contiguous swz range
// [64x, 64x+64) = batches 2x, 2x+1. Same map in both kernels so K1's writes
// are read back from the same XCD's L2.
__device__ __forceinline__ int xcd_swz(int bid) {
    return (bid & 7) * 64 + (bid >> 3);
}

// ---------------------------------------------------------------------------
// K1: 8 flat rows per block, 512 threads. h (LDS), ai (global), g = h@W_out
// (global), ajT[b][k][j] via LDS repack -> float2 stores (16x32B per wave).
// ---------------------------------------------------------------------------
__global__ __launch_bounds__(512, 4) void gat_k1(
    const float* __restrict__ x, const float* __restrict__ W_fc,
    const float* __restrict__ b_fc, const float* __restrict__ W_a1,
    const float* __restrict__ b_a1, const float* __restrict__ W_out,
    float* __restrict__ ai, float* __restrict__ ajT, float* __restrict__ g)
{
    __shared__ __align__(16) float xs[8 * HID];   // phase1 input; later ajtmp
    __shared__ __align__(16) float hs[8 * HID];
    const int tid = threadIdx.x;
    const int k   = tid & 127;
    const int q   = tid >> 7;            // 0..3
    const int swz = xcd_swz(blockIdx.x);
    const int r0  = swz * 8;             // flat row = b*NN + n0
    const int b   = r0 >> 8;
    const int n0  = r0 & 255;

    for (int t = tid; t < 8 * HID; t += 512)
        xs[t] = x[r0 * HID + t];
    __syncthreads();

    // ---- phase 1: h rows 2q, 2q+1 (stays in LDS) ----
    {
        const float bf = b_fc[k];
        float a0 = bf, a1 = bf;
        #pragma unroll 4
        for (int d0 = 0; d0 < HID; d0 += 4) {
            const float w0 = W_fc[(d0 + 0) * HID + k];
            const float w1 = W_fc[(d0 + 1) * HID + k];
            const float w2 = W_fc[(d0 + 2) * HID + k];
            const float w3 = W_fc[(d0 + 3) * HID + k];
            const float4 x0 = *(const float4*)&xs[(2 * q + 0) * HID + d0];
            const float4 x1 = *(const float4*)&xs[(2 * q + 1) * HID + d0];
            a0 += x0.x * w0 + x0.y * w1 + x0.z * w2 + x0.w * w3;
            a1 += x1.x * w0 + x1.y * w1 + x1.z * w2 + x1.w * w3;
        }
        hs[(2 * q + 0) * HID + k] = a0;
        hs[(2 * q + 1) * HID + k] = a1;
    }
    __syncthreads();   // xs dead from here; reused as ajtmp

    float* ajtmp = xs;   // [8 rows][128 k]

    // ---- phase 2a: q0/q1 -> ai (global); q2/q3 -> ajtmp (LDS) ----
    {
        const int is_aj  = q >> 1;
        const int rbase  = (q & 1) * 4;
        const float* Wp  = W_a1 + is_aj * HID * HID;
        const float bias = is_aj ? 0.f : b_a1[k];
        float acc[4] = {bias, bias, bias, bias};
        #pragma unroll 4
        for (int d0 = 0; d0 < HID; d0 += 4) {
            const float w0 = Wp[(d0 + 0) * HID + k];
            const float w1 = Wp[(d0 + 1) * HID + k];
            const float w2 = Wp[(d0 + 2) * HID + k];
            const float w3 = Wp[(d0 + 3) * HID + k];
            #pragma unroll
            for (int r = 0; r < 4; ++r) {
                const float4 hv = *(const float4*)&hs[(rbase + r) * HID + d0];
                acc[r] += hv.x * w0 + hv.y * w1 + hv.z * w2 + hv.w * w3;
            }
        }
        if (!is_aj) {
            #pragma unroll
            for (int r = 0; r < 4; ++r)
                ai[(r0 + rbase + r) * HID + k] = acc[r];
        } else {
            #pragma unroll
            for (int r = 0; r < 4; ++r)
                ajtmp[(rbase + r) * HID + k] = acc[r];
        }
    }

    // ---- phase 2b: g rows 2q,2q+1 = hs @ W_out ----
    {
        float a0 = 0.f, a1 = 0.f;
        #pragma unroll 4
        for (int d0 = 0; d0 < HID; d0 += 4) {
            const float w0 = W_out[(d0 + 0) * HID + k];
            const float w1 = W_out[(d0 + 1) * HID + k];
            const float w2 = W_out[(d0 + 2) * HID + k];
            const float w3 = W_out[(d0 + 3) * HID + k];
            const float4 h0 = *(const float4*)&hs[(2 * q + 0) * HID + d0];
            const float4 h1 = *(const float4*)&hs[(2 * q + 1) * HID + d0];
            a0 += h0.x * w0 + h0.y * w1 + h0.z * w2 + h0.w * w3;
            a1 += h1.x * w0 + h1.y * w1 + h1.z * w2 + h1.w * w3;
        }
        g[(r0 + 2 * q + 0) * HID + k] = a0;
        g[(r0 + 2 * q + 1) * HID + k] = a1;
    }
    __syncthreads();   // ajtmp complete

    // ---- repack store: ajT[b][k][n0..n0+7], float2 per thread ----
    {
        const int kk = tid >> 2;            // 0..127
        const int jj = (tid & 3) * 2;       // 0,2,4,6
        float2 v;
        v.x = ajtmp[(jj + 0) * HID + kk];
        v.y = ajtmp[(jj + 1) * HID + kk];
        *(float2*)&ajT[(b * HID + kk) * NN + n0 + jj] = v;
    }
}

// ---------------------------------------------------------------------------
// K2: per (batch, 8-row i-tile), 512 threads (8 waves). Phase A: wave =
// (row-pair, j-half): 2 rows x 128 j, b64 LDS reads, ai/w2 via uniform
// s_loads, aj LDS-chunked (coalesced, reg prefetch). Softmax: e staged to
// LDS, row-per-wave shuffle reduce. Phase B: 4-way j-split, g read once per
// block, LDS reduction. out = attn@g + b_out.
// ---------------------------------------------------------------------------
__global__ __launch_bounds__(512, 4) void gat_k2(
    const float* __restrict__ ai, const float* __restrict__ ajT,
    const float* __restrict__ g,  const int* __restrict__ adj,
    const float* __restrict__ w_a2, const float* __restrict__ b_a2,
    const float* __restrict__ b_out, float* __restrict__ out)
{
    __shared__ __align__(16) float ov[32 * NN];   // 32KB: ajs; later p_lds+red

    const int tid  = threadIdx.x;
    const int swz  = xcd_swz(blockIdx.x);
    const int b    = swz >> 5;
    const int i0   = (swz & 31) * 8;
    const int wid  = tid >> 6, lane = tid & 63;

    // staging map: thread covers ajs[srow][sc0 + 64u + 0..3], u=0..3
    const int srow = tid >> 4;            // 0..31
    const int sc0  = (tid & 15) * 4;
    const float* ajbase = ajT + (b * HID + srow) * NN + sc0;

    float4 st[4];
    #pragma unroll
    for (int u = 0; u < 4; ++u) st[u] = *(const float4*)(ajbase + 64 * u);

    // phase A wave role: row-pair rp (rows 2rp,2rp+1), j-half jh
    const int rp = wid >> 1, jh = wid & 1;
    const int jb = jh * 128 + 2 * lane;   // this lane's 2 j's

    const int rb = __builtin_amdgcn_readfirstlane((b * NN + i0 + 2 * rp) * HID);
    const float* ai0 = ai + rb;
    const float* ai1 = ai + rb + HID;

    float2 acc0 = {0.f, 0.f}, acc1 = {0.f, 0.f};
    for (int kc = 0; kc < 4; ++kc) {
        __syncthreads();   // previous chunk consumed
        #pragma unroll
        for (int u = 0; u < 4; ++u)
            *(float4*)&ov[srow * NN + sc0 + 64 * u] = st[u];
        if (kc < 3) {
            const float* nxt = ajbase + (kc + 1) * 32 * NN;
            #pragma unroll
            for (int u = 0; u < 4; ++u) st[u] = *(const float4*)(nxt + 64 * u);
        }
        __syncthreads();   // chunk ready
        const int kb = kc * 32;
        #pragma unroll 8
        for (int kk = 0; kk < 32; ++kk) {
            const float2 a2 = *(const float2*)&ov[kk * NN + jb];
            const float v0 = ai0[kb + kk];
            const float v1 = ai1[kb + kk];
            const float wv = w_a2[kb + kk];
            acc0.x += fmaxf(v0 + a2.x, 0.f) * wv;
            acc0.y += fmaxf(v0 + a2.y, 0.f) * wv;
            acc1.x += fmaxf(v1 + a2.x, 0.f) * wv;
            acc1.y += fmaxf(v1 + a2.y, 0.f) * wv;
        }
    }
    __syncthreads();       // ajs dead; ov reusable

    float* p_lds = ov;            // [8][NN]       8KB
    float* red   = ov + 8 * NN;   // [4][8][128]  16KB

    // ---- mask + bias, stage e to LDS ----
    {
        const float ba2 = b_a2[0];
        const int arow = (b * NN + i0 + 2 * rp) * NN + jb;
        const int2 m0 = *(const int2*)(adj + arow);
        const int2 m1 = *(const int2*)(adj + arow + NN);
        float2 e0, e1;
        e0.x = m0.x ? acc0.x + ba2 : -1e9f;
        e0.y = m0.y ? acc0.y + ba2 : -1e9f;
        e1.x = m1.x ? acc1.x + ba2 : -1e9f;
        e1.y = m1.y ? acc1.y + ba2 : -1e9f;
        *(float2*)&p_lds[(2 * rp + 0) * NN + jb] = e0;
        *(float2*)&p_lds[(2 * rp + 1) * NN + jb] = e1;
    }
    __syncthreads();

    // ---- softmax: wave wid owns row wid ----
    {
        float4 e4 = *(const float4*)&p_lds[wid * NN + 4 * lane];
        float m = fmaxf(fmaxf(e4.x, e4.y), fmaxf(e4.z, e4.w));
        #pragma unroll
        for (int off = 32; off; off >>= 1) m = fmaxf(m, __shfl_xor(m, off));
        const float p0 = __expf(e4.x - m), p1 = __expf(e4.y - m);
        const float p2 = __expf(e4.z - m), p3 = __expf(e4.w - m);
        float s = (p0 + p1) + (p2 + p3);
        #pragma unroll
        for (int off = 32; off; off >>= 1) s += __shfl_xor(s, off);
        const float inv = 1.f / s;
        const float4 pv = {p0 * inv, p1 * inv, p2 * inv, p3 * inv};
        *(float4*)&p_lds[wid * NN + 4 * lane] = pv;
    }
    __syncthreads();

    // ---- phase B: out = attn @ g + b_out, j split in 4 quarters ----
    const int k = tid & 127, qh = tid >> 7;   // j in [64qh, 64qh+64)
    {
        float acc[8] = {0.f, 0.f, 0.f, 0.f, 0.f, 0.f, 0.f, 0.f};
        const float* gb = g + (b * NN + qh * 64) * HID + k;
        #pragma unroll 4
        for (int jq = 0; jq < 16; ++jq) {
            const float g0 = gb[(4 * jq + 0) * HID];
            const float g1 = gb[(4 * jq + 1) * HID];
            const float g2 = gb[(4 * jq + 2) * HID];
            const float g3 = gb[(4 * jq + 3) * HID];
            #pragma unroll
            for (int r = 0; r < 8; ++r) {
                const float4 pv = *(const float4*)&p_lds[r * NN + qh * 64 + 4 * jq];
                acc[r] += pv.x * g0 + pv.y * g1 + pv.z * g2 + pv.w * g3;
            }
        }
        #pragma unroll
        for (int r = 0; r < 8; ++r) red[(qh * 8 + r) * 128 + k] = acc[r];
    }
    __syncthreads();

    // ---- final reduce: thread handles rows 2qh, 2qh+1 ----
    {
        const float bo = b_out[k];
        #pragma unroll
        for (int r2 = 0; r2 < 2; ++r2) {
            const int r = qh * 2 + r2;
            const float v = red[(0 * 8 + r) * 128 + k] + red[(1 * 8 + r) * 128 + k]
                          + red[(2 * 8 + r) * 128 + k] + red[(3 * 8 + r) * 128 + k];
            out[(b * NN + i0 + r) * HID + k] = v + bo;
        }
    }
}

extern "C" void kernel_launch(void* const* d_in, const int* in_sizes, int n_in,
                              void* d_out, int out_size, void* d_ws, size_t ws_size,
                              hipStream_t stream) {
    const float* x     = (const float*)d_in[0];
    const int*   adj   = (const int*)  d_in[1];
    const float* W_fc  = (const float*)d_in[2];
    const float* b_fc  = (const float*)d_in[3];
    const float* W_a1  = (const float*)d_in[4];
    const float* b_a1  = (const float*)d_in[5];
    const float* w_a2  = (const float*)d_in[6];
    const float* b_a2  = (const float*)d_in[7];
    const float* W_out = (const float*)d_in[8];
    const float* b_out = (const float*)d_in[9];
    float* out = (float*)d_out;

    float* ws  = (float*)d_ws;
    float* ai  = ws;                      // 16*256*128
    float* ajT = ws + BS * NN * HID;      // +524288, ajT[b][k][j]
    float* g   = ws + 2 * BS * NN * HID;  // +1048576, g = h@W_out

    gat_k1<<<BS * NN / 8, 512, 0, stream>>>(x, W_fc, b_fc, W_a1, b_a1, W_out,
                                            ai, ajT, g);
    gat_k2<<<BS * (NN / 8), 512, 0, stream>>>(ai, ajT, g, adj, w_a2, b_a2,
                                              b_out, out);
}

// Round 7
// 42.878 us; speedup vs baseline: 1.6064x; 1.5441x over previous
//
#include <hip/hip_runtime.h>

#define BS  16
#define NN  256
#define HID 128

// XCD-aware swizzle for 1024 blocks: XCD x gets swz in [128x, 128x+128)
// = 2 consecutive batches. Same map in K1 and K2 (intra-kernel L2 locality;
// cross-kernel reuse is impossible — L2 is flushed at kernel boundaries).
__device__ __forceinline__ int xcd_swz(int bid) {
    return (bid & 7) * 128 + (bid >> 3);
}

// ---------------------------------------------------------------------------
// K1: 4 flat rows per block, 256 threads (thread = (k, q), q in {0,1}).
// h (LDS only), ai (global), g = h@W_out (global), ajT[b][k][j] via LDS
// repack. No barriers except the 3 structural ones.
// ---------------------------------------------------------------------------
__global__ __launch_bounds__(256, 4) void gat_k1(
    const float* __restrict__ x, const float* __restrict__ W_fc,
    const float* __restrict__ b_fc, const float* __restrict__ W_a1,
    const float* __restrict__ b_a1, const float* __restrict__ W_out,
    float* __restrict__ ai, float* __restrict__ ajT, float* __restrict__ g)
{
    __shared__ __align__(16) float xs[4 * HID];
    __shared__ __align__(16) float hs[4 * HID];
    __shared__ __align__(16) float ajtmp[4 * HID];

    const int tid = threadIdx.x;
    const int k   = tid & 127;
    const int q   = tid >> 7;                 // 0..1
    const int swz = xcd_swz(blockIdx.x);
    const int r0  = swz * 4;                  // flat row = b*NN + n0
    const int b   = r0 >> 8;
    const int n0  = r0 & 255;

    if (tid < 128)
        *(float4*)&xs[tid * 4] = *(const float4*)&x[r0 * HID + tid * 4];
    __syncthreads();

    // ---- phase 1: h rows 2q, 2q+1 (split accumulator chains) ----
    {
        const float bf = b_fc[k];
        float a0a = bf, a0b = 0.f, a1a = bf, a1b = 0.f;
        #pragma unroll 4
        for (int d0 = 0; d0 < HID; d0 += 8) {
            float w[8];
            #pragma unroll
            for (int t = 0; t < 8; ++t) w[t] = W_fc[(d0 + t) * HID + k];
            const float4 xA0 = *(const float4*)&xs[(2 * q + 0) * HID + d0];
            const float4 xA1 = *(const float4*)&xs[(2 * q + 0) * HID + d0 + 4];
            const float4 xB0 = *(const float4*)&xs[(2 * q + 1) * HID + d0];
            const float4 xB1 = *(const float4*)&xs[(2 * q + 1) * HID + d0 + 4];
            a0a += xA0.x * w[0] + xA0.y * w[1] + xA0.z * w[2] + xA0.w * w[3];
            a0b += xA1.x * w[4] + xA1.y * w[5] + xA1.z * w[6] + xA1.w * w[7];
            a1a += xB0.x * w[0] + xB0.y * w[1] + xB0.z * w[2] + xB0.w * w[3];
            a1b += xB1.x * w[4] + xB1.y * w[5] + xB1.z * w[6] + xB1.w * w[7];
        }
        hs[(2 * q + 0) * HID + k] = a0a + a0b;
        hs[(2 * q + 1) * HID + k] = a1a + a1b;
    }
    __syncthreads();

    // ---- phase 2a: q=0 -> ai rows 0..3; q=1 -> aj rows 0..3 (LDS) ----
    {
        const float* Wp  = W_a1 + q * HID * HID;
        const float bias = q ? 0.f : b_a1[k];
        float acc[4][2];
        #pragma unroll
        for (int r = 0; r < 4; ++r) { acc[r][0] = bias; acc[r][1] = 0.f; }
        #pragma unroll 2
        for (int d0 = 0; d0 < HID; d0 += 8) {
            float w[8];
            #pragma unroll
            for (int t = 0; t < 8; ++t) w[t] = Wp[(d0 + t) * HID + k];
            #pragma unroll
            for (int r = 0; r < 4; ++r) {
                const float4 h0 = *(const float4*)&hs[r * HID + d0];
                const float4 h1 = *(const float4*)&hs[r * HID + d0 + 4];
                acc[r][0] += h0.x * w[0] + h0.y * w[1] + h0.z * w[2] + h0.w * w[3];
                acc[r][1] += h1.x * w[4] + h1.y * w[5] + h1.z * w[6] + h1.w * w[7];
            }
        }
        if (!q) {
            #pragma unroll
            for (int r = 0; r < 4; ++r)
                ai[(r0 + r) * HID + k] = acc[r][0] + acc[r][1];
        } else {
            #pragma unroll
            for (int r = 0; r < 4; ++r)
                ajtmp[r * HID + k] = acc[r][0] + acc[r][1];
        }
    }

    // ---- phase 2b: g rows 2q,2q+1 = hs @ W_out ----
    {
        float a0a = 0.f, a0b = 0.f, a1a = 0.f, a1b = 0.f;
        #pragma unroll 4
        for (int d0 = 0; d0 < HID; d0 += 8) {
            float w[8];
            #pragma unroll
            for (int t = 0; t < 8; ++t) w[t] = W_out[(d0 + t) * HID + k];
            const float4 hA0 = *(const float4*)&hs[(2 * q + 0) * HID + d0];
            const float4 hA1 = *(const float4*)&hs[(2 * q + 0) * HID + d0 + 4];
            const float4 hB0 = *(const float4*)&hs[(2 * q + 1) * HID + d0];
            const float4 hB1 = *(const float4*)&hs[(2 * q + 1) * HID + d0 + 4];
            a0a += hA0.x * w[0] + hA0.y * w[1] + hA0.z * w[2] + hA0.w * w[3];
            a0b += hA1.x * w[4] + hA1.y * w[5] + hA1.z * w[6] + hA1.w * w[7];
            a1a += hB0.x * w[0] + hB0.y * w[1] + hB0.z * w[2] + hB0.w * w[3];
            a1b += hB1.x * w[4] + hB1.y * w[5] + hB1.z * w[6] + hB1.w * w[7];
        }
        g[(r0 + 2 * q + 0) * HID + k] = a0a + a0b;
        g[(r0 + 2 * q + 1) * HID + k] = a1a + a1b;
    }
    __syncthreads();   // ajtmp ready

    // ---- repack store: ajT[b][k][n0+jj], float2 per thread ----
    {
        const int kk = tid >> 1;
        const int jj = (tid & 1) * 2;
        float2 v;
        v.x = ajtmp[(jj + 0) * HID + kk];
        v.y = ajtmp[(jj + 1) * HID + kk];
        *(float2*)&ajT[(b * HID + kk) * NN + n0 + jj] = v;
    }
}

// ---------------------------------------------------------------------------
// K2: 4-row i-tile per block, 256 threads (4 waves). Phase A: wave = all 4
// rows x 64-j quarter, aj read DIRECT from global (L2-resident per XCD, no
// staging barriers), ai/w2 as LDS broadcasts. Softmax: 1 row per wave,
// wave-local shuffles. Phase B: g direct from global, 2-way j-split + LDS
// reduce. out = attn@g + b_out.
// ---------------------------------------------------------------------------
__global__ __launch_bounds__(256, 4) void gat_k2(
    const float* __restrict__ ai, const float* __restrict__ ajT,
    const float* __restrict__ g,  const int* __restrict__ adj,
    const float* __restrict__ w_a2, const float* __restrict__ b_a2,
    const float* __restrict__ b_out, float* __restrict__ out)
{
    __shared__ __align__(16) float4 aw4[HID];        // {ai rows 0..3} per k
    __shared__ __align__(16) float  w2s[HID];
    __shared__ __align__(16) float  ep[4][NN];       // e, then p
    __shared__ __align__(16) float  red[2][4][HID];

    const int tid = threadIdx.x;
    const int swz = xcd_swz(blockIdx.x);
    const int b   = swz >> 6;
    const int i0  = (swz & 63) * 4;
    const int wv  = tid >> 6, lane = tid & 63;

    if (tid < 128) {
        float4 v;
        v.x = ai[(b * NN + i0 + 0) * HID + tid];
        v.y = ai[(b * NN + i0 + 1) * HID + tid];
        v.z = ai[(b * NN + i0 + 2) * HID + tid];
        v.w = ai[(b * NN + i0 + 3) * HID + tid];
        aw4[tid] = v;
        w2s[tid] = w_a2[tid];
    }
    __syncthreads();

    // ---- phase A: e[i0..i0+3][j], j = wv*64 + lane ----
    const int j = wv * 64 + lane;
    {
        const float* ajp = ajT + b * HID * NN + j;
        float acc[4] = {0.f, 0.f, 0.f, 0.f};
        #pragma unroll 8
        for (int kk = 0; kk < HID; ++kk) {
            const float a  = ajp[kk * NN];
            const float4 av = aw4[kk];
            const float wk = w2s[kk];
            acc[0] += fmaxf(av.x + a, 0.f) * wk;
            acc[1] += fmaxf(av.y + a, 0.f) * wk;
            acc[2] += fmaxf(av.z + a, 0.f) * wk;
            acc[3] += fmaxf(av.w + a, 0.f) * wk;
        }
        const float ba2 = b_a2[0];
        #pragma unroll
        for (int r = 0; r < 4; ++r) {
            const int am = adj[(b * NN + i0 + r) * NN + j];
            ep[r][j] = am ? acc[r] + ba2 : -1e9f;
        }
    }
    __syncthreads();

    // ---- softmax: wave wv owns row wv ----
    {
        float4 e4 = *(const float4*)&ep[wv][4 * lane];
        float m = fmaxf(fmaxf(e4.x, e4.y), fmaxf(e4.z, e4.w));
        #pragma unroll
        for (int off = 32; off; off >>= 1) m = fmaxf(m, __shfl_xor(m, off));
        const float p0 = __expf(e4.x - m), p1 = __expf(e4.y - m);
        const float p2 = __expf(e4.z - m), p3 = __expf(e4.w - m);
        float s = (p0 + p1) + (p2 + p3);
        #pragma unroll
        for (int off = 32; off; off >>= 1) s += __shfl_xor(s, off);
        const float inv = 1.f / s;
        const float4 pv = {p0 * inv, p1 * inv, p2 * inv, p3 * inv};
        *(float4*)&ep[wv][4 * lane] = pv;
    }
    __syncthreads();

    // ---- phase B: out = attn @ g + b_out, j split in halves ----
    const int k = tid & 127, qh = tid >> 7;   // j in [128qh, 128qh+128)
    {
        float o[4] = {0.f, 0.f, 0.f, 0.f};
        const float* gb = g + (b * NN + qh * 128) * HID + k;
        const int jb = qh * 128;
        #pragma unroll 2
        for (int jq = 0; jq < 128; jq += 4) {
            const float g0 = gb[(jq + 0) * HID];
            const float g1 = gb[(jq + 1) * HID];
            const float g2 = gb[(jq + 2) * HID];
            const float g3 = gb[(jq + 3) * HID];
            const float4 pA = *(const float4*)&ep[0][jb + jq];
            const float4 pB = *(const float4*)&ep[1][jb + jq];
            const float4 pC = *(const float4*)&ep[2][jb + jq];
            const float4 pD = *(const float4*)&ep[3][jb + jq];
            o[0] += pA.x * g0 + pA.y * g1 + pA.z * g2 + pA.w * g3;
            o[1] += pB.x * g0 + pB.y * g1 + pB.z * g2 + pB.w * g3;
            o[2] += pC.x * g0 + pC.y * g1 + pC.z * g2 + pC.w * g3;
            o[3] += pD.x * g0 + pD.y * g1 + pD.z * g2 + pD.w * g3;
        }
        #pragma unroll
        for (int r = 0; r < 4; ++r) red[qh][r][k] = o[r];
    }
    __syncthreads();

    // ---- final reduce: qh handles rows 2qh, 2qh+1 ----
    {
        const float bo = b_out[k];
        #pragma unroll
        for (int r2 = 0; r2 < 2; ++r2) {
            const int r = 2 * qh + r2;
            out[(b * NN + i0 + r) * HID + k] =
                red[0][r][k] + red[1][r][k] + bo;
        }
    }
}

extern "C" void kernel_launch(void* const* d_in, const int* in_sizes, int n_in,
                              void* d_out, int out_size, void* d_ws, size_t ws_size,
                              hipStream_t stream) {
    const float* x     = (const float*)d_in[0];
    const int*   adj   = (const int*)  d_in[1];
    const float* W_fc  = (const float*)d_in[2];
    const float* b_fc  = (const float*)d_in[3];
    const float* W_a1  = (const float*)d_in[4];
    const float* b_a1  = (const float*)d_in[5];
    const float* w_a2  = (const float*)d_in[6];
    const float* b_a2  = (const float*)d_in[7];
    const float* W_out = (const float*)d_in[8];
    const float* b_out = (const float*)d_in[9];
    float* out = (float*)d_out;

    float* ws  = (float*)d_ws;
    float* ai  = ws;                      // 16*256*128
    float* ajT = ws + BS * NN * HID;      // +524288, ajT[b][k][j]
    float* g   = ws + 2 * BS * NN * HID;  // +1048576, g = h@W_out

    gat_k1<<<BS * NN / 4, 256, 0, stream>>>(x, W_fc, b_fc, W_a1, b_a1, W_out,
                                            ai, ajT, g);
    gat_k2<<<BS * (NN / 4), 256, 0, stream>>>(ai, ajT, g, adj, w_a2, b_a2,
                                              b_out, out);
}